// Round 4
// baseline (423.939 us; speedup 1.0000x reference)
//
#include <hip/hip_runtime.h>

#define LQ     22500
#define SPA_H  58
#define SPA_W  100
#define S_TOT  5800
#define NCAMS  6
#define CDIM   256
#define NB_VAL 1088  // ceil(34800/32)
#define NB_Q   704   // ceil(22500/32)
#define NB_VIS 88    // ceil(22500/256)
#define NB_OUT 704   // ceil(22500/32)

typedef __attribute__((ext_vector_type(8))) _Float16 half8;
typedef __attribute__((ext_vector_type(4))) _Float16 half4;
typedef __attribute__((ext_vector_type(4))) float f32x4;
typedef __attribute__((ext_vector_type(2))) float f32x2;

__device__ __forceinline__ half8 cvt_f32x8(const float* p) {
  f32x4 a = *(const f32x4*)p;
  f32x4 b = *(const f32x4*)(p + 4);
  half8 r;
  r[0] = (_Float16)a.x; r[1] = (_Float16)a.y; r[2] = (_Float16)a.z; r[3] = (_Float16)a.w;
  r[4] = (_Float16)b.x; r[5] = (_Float16)b.y; r[6] = (_Float16)b.z; r[7] = (_Float16)b.w;
  return r;
}

// C[M x N] = A[M x 256] @ W[N x 256]^T + bias.  32-row M-tile, 4 waves own
// disjoint column ranges.  A,W f32 with inline f16 cvt.
// BSEL=1: W/bias split at col 128 (W_off ++ W_attn).
// OUT_MODE: 0 = f32 out with per-row scale (out_gemm; outA may alias A ->
//               __syncthreads between K-loop and epilogue, block-local rows);
//           2 = f16 out (value GEMM);
//           3 = query special: cols<128 -> pre-scaled f16 offsets to outA,
//               cols>=128 -> per-head-octet softmax (shfl_xor) -> f32 outB.
template<int N, int OUT_MODE, int BSEL>
__device__ __forceinline__ void gemm_body(
    const float* __restrict__ A, const float* __restrict__ W0,
    const float* __restrict__ W1, const float* __restrict__ b0,
    const float* __restrict__ b1, void* __restrict__ outA,
    float* __restrict__ outB, const float* __restrict__ rowscale,
    int M, int bid)
{
  constexpr int K  = CDIM;
  constexpr int NT = (N / 4) / 16;
  const int lane = threadIdx.x & 63;
  const int wave = threadIdx.x >> 6;
  const int m15  = lane & 15;
  const int quad = lane >> 4;
  const int rowbase = bid * 32;
  const int colbase = wave * (N / 4);

  const float* wp[NT];
  float bv[NT];
#pragma unroll
  for (int t = 0; t < NT; ++t) {
    const int c = colbase + t * 16 + m15;
    if (BSEL == 0) { wp[t] = W0 + (size_t)c * K; bv[t] = b0[c]; }
    else {
      wp[t] = (c < 128) ? (W0 + (size_t)c * K) : (W1 + (size_t)(c - 128) * K);
      bv[t] = (c < 128) ? b0[c] : b1[c - 128];
    }
  }

  f32x4 acc[2][NT];
#pragma unroll
  for (int rt = 0; rt < 2; ++rt)
#pragma unroll
    for (int t = 0; t < NT; ++t) acc[rt][t] = (f32x4){0.f, 0.f, 0.f, 0.f};

#pragma unroll
  for (int kk = 0; kk < K; kk += 32) {
    const int ko = kk + quad * 8;
    half8 a[2], b[NT];
#pragma unroll
    for (int rt = 0; rt < 2; ++rt) {
      int row = rowbase + rt * 16 + m15;
      row = row < M ? row : M - 1;
      a[rt] = cvt_f32x8(A + (size_t)row * K + ko);
    }
#pragma unroll
    for (int t = 0; t < NT; ++t) b[t] = cvt_f32x8(wp[t] + ko);
#pragma unroll
    for (int t = 0; t < NT; ++t)
#pragma unroll
      for (int rt = 0; rt < 2; ++rt)
        acc[rt][t] = __builtin_amdgcn_mfma_f32_16x16x32_f16(a[rt], b[t], acc[rt][t], 0, 0, 0);
  }

  if (OUT_MODE == 0) __syncthreads();  // A may alias outA (block-local rows)

  float rs[2][4];
  if (OUT_MODE == 0) {
#pragma unroll
    for (int rt = 0; rt < 2; ++rt)
#pragma unroll
      for (int i = 0; i < 4; ++i) {
        int r = rowbase + rt * 16 + quad * 4 + i;
        rs[rt][i] = rowscale[r < M ? r : M - 1];
      }
  }

#pragma unroll
  for (int rt = 0; rt < 2; ++rt) {
    const int orow = rowbase + rt * 16 + quad * 4;
#pragma unroll
    for (int t = 0; t < NT; ++t) {
      const int col = colbase + t * 16 + m15;
      if (OUT_MODE == 3) {
        if (col >= 128) {
          // per-(row,head) softmax over the 8-lane octet holding this head
#pragma unroll
          for (int i = 0; i < 4; ++i) {
            const float v = acc[rt][t][i] + bv[t];
            float mx = v;
            mx = fmaxf(mx, __shfl_xor(mx, 1, 64));
            mx = fmaxf(mx, __shfl_xor(mx, 2, 64));
            mx = fmaxf(mx, __shfl_xor(mx, 4, 64));
            const float e = __expf(v - mx);
            float sm = e;
            sm += __shfl_xor(sm, 1, 64);
            sm += __shfl_xor(sm, 2, 64);
            sm += __shfl_xor(sm, 4, 64);
            const int r = orow + i;
            if (r < M) outB[(size_t)r * 64 + (col - 128)] = e / sm;
          }
        } else {
          const float sc = (col & 1) ? (1.f / SPA_H) : (1.f / SPA_W);
#pragma unroll
          for (int i = 0; i < 4; ++i) {
            const int r = orow + i;
            if (r < M)
              ((_Float16*)outA)[(size_t)r * 128 + col] =
                  (_Float16)((acc[rt][t][i] + bv[t]) * sc);
          }
        }
      } else if (OUT_MODE == 0) {
#pragma unroll
        for (int i = 0; i < 4; ++i) {
          const int r = orow + i;
          if (r < M)
            ((float*)outA)[(size_t)r * N + col] = acc[rt][t][i] * rs[rt][i] + bv[t];
        }
      } else {
#pragma unroll
        for (int i = 0; i < 4; ++i) {
          const int r = orow + i;
          if (r < M)
            ((_Float16*)outA)[(size_t)r * N + col] = (_Float16)(acc[rt][t][i] + bv[t]);
        }
      }
    }
  }
}

// per-query 1/visible-count
__device__ __forceinline__ void vis_body(const int* __restrict__ bev,
                                         float* __restrict__ invc, int idx) {
  if (idx >= LQ) return;
  int cnt = 0;
#pragma unroll
  for (int c = 0; c < NCAMS; ++c) {
    const int4 b4 = *(const int4*)(bev + ((size_t)c * LQ + idx) * 4);
    cnt += (b4.x + b4.y + b4.z + b4.w) > 0 ? 1 : 0;
  }
  invc[idx] = 1.f / (float)(cnt > 0 ? cnt : 1);
}

// Fused front-end: [0,1088) value GEMM, [1088,1792) query GEMM (off f16 +
// softmaxed weights f32), [1792,1880) visibility counts.
__global__ __launch_bounds__(256, 2) void fused_front(
    const float* __restrict__ value, const float* __restrict__ query,
    const int* __restrict__ bev,
    const float* __restrict__ W_val, const float* __restrict__ b_val,
    const float* __restrict__ W_off, const float* __restrict__ b_off,
    const float* __restrict__ W_attn, const float* __restrict__ b_attn,
    _Float16* __restrict__ vp, _Float16* __restrict__ offb,
    float* __restrict__ wbuf, float* __restrict__ invc) {
  const int bid = blockIdx.x;
  if (bid < NB_VAL)
    gemm_body<256, 2, 0>(value, W_val, nullptr, b_val, nullptr, vp, nullptr,
                         nullptr, NCAMS * S_TOT, bid);
  else if (bid < NB_VAL + NB_Q)
    gemm_body<192, 3, 1>(query, W_off, W_attn, b_off, b_attn, offb, wbuf,
                         nullptr, LQ, bid - NB_VAL);
  else
    vis_body(bev, invc, (bid - NB_VAL - NB_Q) * 256 + (int)threadIdx.x);
}

// out = (slots_raw * invc) @ W_out^T + b_out; slots_raw aliases d_out.
__global__ __launch_bounds__(256, 2) void out_gemm(
    const float* __restrict__ slots, const float* __restrict__ W_out,
    const float* __restrict__ b_out, const float* __restrict__ invc,
    float* __restrict__ out) {
  gemm_body<256, 0, 0>(slots, W_out, nullptr, b_out, nullptr, out, nullptr,
                       invc, LQ, blockIdx.x);
}

// One camera per launch (per-cam 2.97 MB value slice is L2-resident).
// 32 lanes/query, 2-point-deep software pipeline: point p+1's 4 taps issue
// before point p's FMAs consume.  Raw f32 sums accumulate into d_out.
#define TAPCOMP(P, S)                                                           \
  const float x_##S = (s_ref[ql][((P)&3)*2+0] + s_off[ql][(h8+(P))*2+0]) * 100.f - 0.5f; \
  const float y_##S = (s_ref[ql][((P)&3)*2+1] + s_off[ql][(h8+(P))*2+1]) * 58.f - 0.5f;  \
  const float x0f_##S = floorf(x_##S), y0f_##S = floorf(y_##S);                 \
  const float fx_##S = x_##S - x0f_##S, fy_##S = y_##S - y0f_##S;               \
  const int x0_##S = (int)x0f_##S, y0_##S = (int)y0f_##S;                       \
  const float wgt_##S = s_w[ql][h8 + (P)];                                      \
  const float gy0_##S = (1.f - fy_##S) * wgt_##S, gy1_##S = fy_##S * wgt_##S;   \
  const float vx0_##S = ((unsigned)x0_##S < SPA_W) ? 1.f : 0.f;                 \
  const float vx1_##S = ((unsigned)(x0_##S + 1) < SPA_W) ? 1.f : 0.f;           \
  const float vy0_##S = ((unsigned)y0_##S < SPA_H) ? 1.f : 0.f;                 \
  const float vy1_##S = ((unsigned)(y0_##S + 1) < SPA_H) ? 1.f : 0.f;           \
  const float w00_##S = gy0_##S * (1.f - fx_##S) * (vy0_##S * vx0_##S);         \
  const float w01_##S = gy0_##S * fx_##S * (vy0_##S * vx1_##S);                 \
  const float w10_##S = gy1_##S * (1.f - fx_##S) * (vy1_##S * vx0_##S);         \
  const float w11_##S = gy1_##S * fx_##S * (vy1_##S * vx1_##S);                 \
  const int x0c_##S = min(max(x0_##S, 0), SPA_W - 1);                           \
  const int x1c_##S = min(max(x0_##S + 1, 0), SPA_W - 1);                       \
  const int y0c_##S = min(max(y0_##S, 0), SPA_H - 1);                           \
  const int y1c_##S = min(max(y0_##S + 1, 0), SPA_H - 1);                       \
  const int r0_##S = y0c_##S * SPA_W, r1_##S = y1c_##S * SPA_W;                 \
  const half8 a00_##S = *(const half8*)(vpc + ((size_t)(r0_##S + x0c_##S) << 8)); \
  const half8 a01_##S = *(const half8*)(vpc + ((size_t)(r0_##S + x1c_##S) << 8)); \
  const half8 a10_##S = *(const half8*)(vpc + ((size_t)(r1_##S + x0c_##S) << 8)); \
  const half8 a11_##S = *(const half8*)(vpc + ((size_t)(r1_##S + x1c_##S) << 8));

#define TAPFMA(S)                                                               \
  _Pragma("unroll")                                                             \
  for (int i = 0; i < 8; ++i) {                                                 \
    float v = acc[i];                                                           \
    v = fmaf(w00_##S, (float)a00_##S[i], v);                                    \
    v = fmaf(w01_##S, (float)a01_##S[i], v);                                    \
    v = fmaf(w10_##S, (float)a10_##S[i], v);                                    \
    v = fmaf(w11_##S, (float)a11_##S[i], v);                                    \
    acc[i] = v;                                                                 \
  }

template<int PASS0>
__global__ __launch_bounds__(256, 4) void sampler_pass(
    const _Float16* __restrict__ vp,     // (6, 5800, 256) f16
    const _Float16* __restrict__ offb,   // (LQ, 128) f16, pre-scaled
    const float* __restrict__ wbuf,      // (LQ, 64) f32, softmaxed
    const float* __restrict__ ref,       // f32 (6, 1, LQ, 4, 2)
    const int* __restrict__ bev,         // int32 (6, 1, LQ, 4)
    float* __restrict__ slots,           // (LQ, 256) f32 raw accumulator (= d_out)
    int cam)
{
  const int t    = threadIdx.x;
  const int ql   = t >> 5;
  const int s    = t & 31;
  const int h    = s >> 2;
  const int quad = s & 3;
  const int q    = blockIdx.x * 8 + ql;
  const bool qok = q < LQ;

  __shared__ float s_off[8][128];
  __shared__ float s_w[8][64];
  __shared__ float s_ref[8][8];
  __shared__ int   s_vis[8];

  if (qok) {
    const _Float16* op = offb + (size_t)q * 128;
    const half4 o4 = *(const half4*)(op + s * 4);
#pragma unroll
    for (int k = 0; k < 4; ++k) s_off[ql][s * 4 + k] = (float)o4[k];
    const f32x2 w2 = *(const f32x2*)(wbuf + (size_t)q * 64 + s * 2);
    s_w[ql][s * 2]     = w2.x;
    s_w[ql][s * 2 + 1] = w2.y;
    if (s < 8) s_ref[ql][s] = ref[((size_t)cam * LQ + q) * 8 + s];
  }
  if (s == 0) {
    int v = 0;
    if (qok) {
      const int4 b4 = *(const int4*)(bev + ((size_t)cam * LQ + q) * 4);
      v = (b4.x + b4.y + b4.z + b4.w) > 0 ? 1 : 0;
    }
    s_vis[ql] = v;
  }
  __syncthreads();

  const bool vis = s_vis[ql] != 0;
  float acc[8];
#pragma unroll
  for (int i = 0; i < 8; ++i) acc[i] = 0.f;

  const int h8 = h * 8;
  const _Float16* vpc = vp + (size_t)cam * (S_TOT * CDIM) + h * 32 + quad * 8;

  if (vis) {
    TAPCOMP(0, p0)
    TAPCOMP(1, p1)
    TAPFMA(p0)
    TAPCOMP(2, p2)
    TAPFMA(p1)
    TAPCOMP(3, p3)
    TAPFMA(p2)
    TAPCOMP(4, p4)
    TAPFMA(p3)
    TAPCOMP(5, p5)
    TAPFMA(p4)
    TAPCOMP(6, p6)
    TAPFMA(p5)
    TAPCOMP(7, p7)
    TAPFMA(p6)
    TAPFMA(p7)
  }

  if (qok) {
    float* sp = slots + (size_t)q * CDIM + h * 32 + quad * 8;
    if (PASS0) {
      f32x4 o0, o1;
#pragma unroll
      for (int i = 0; i < 4; ++i) { o0[i] = acc[i]; o1[i] = acc[4 + i]; }
      *(f32x4*)sp = o0;
      *(f32x4*)(sp + 4) = o1;
    } else if (vis) {
      f32x4 o0 = *(const f32x4*)sp;
      f32x4 o1 = *(const f32x4*)(sp + 4);
#pragma unroll
      for (int i = 0; i < 4; ++i) { o0[i] += acc[i]; o1[i] += acc[4 + i]; }
      *(f32x4*)sp = o0;
      *(f32x4*)(sp + 4) = o1;
    }
  }
}

extern "C" void kernel_launch(void* const* d_in, const int* in_sizes, int n_in,
                              void* d_out, int out_size, void* d_ws, size_t ws_size,
                              hipStream_t stream) {
  const float* query  = (const float*)d_in[0];
  const float* refpts = (const float*)d_in[1];
  const int*   bev    = (const int*)d_in[2];
  const float* value  = (const float*)d_in[3];
  const float* W_off  = (const float*)d_in[4];
  const float* b_off  = (const float*)d_in[5];
  const float* W_attn = (const float*)d_in[6];
  const float* b_attn = (const float*)d_in[7];
  const float* W_val  = (const float*)d_in[8];
  const float* b_val  = (const float*)d_in[9];
  const float* W_out  = (const float*)d_in[10];
  const float* b_out  = (const float*)d_in[11];

  char* ws = (char*)d_ws;
  _Float16* vp   = (_Float16*)(ws + 0);          // 34800*256 f16 = 17,817,600
  _Float16* offb = (_Float16*)(ws + 17817600);   // 22500*128 f16 =  5,760,000
  float*    wbuf = (float*)   (ws + 23577600);   // 22500*64  f32 =  5,760,000
  float*    invc = (float*)   (ws + 29337600);   // 22500 f32     =     90,000
                                                 // total: 29,427,600 B
  float* slots = (float*)d_out;                  // raw sums accumulate in d_out

  fused_front<<<NB_VAL + NB_Q + NB_VIS, 256, 0, stream>>>(
      value, query, bev, W_val, b_val, W_off, b_off, W_attn, b_attn,
      vp, offb, wbuf, invc);

  sampler_pass<1><<<(LQ + 7) / 8, 256, 0, stream>>>(vp, offb, wbuf, refpts, bev, slots, 0);
  for (int cam = 1; cam < NCAMS; ++cam)
    sampler_pass<0><<<(LQ + 7) / 8, 256, 0, stream>>>(vp, offb, wbuf, refpts, bev, slots, cam);

  out_gemm<<<NB_OUT, 256, 0, stream>>>(slots, W_out, b_out, invc, (float*)d_out);
}